// Round 6
// baseline (3130.142 us; speedup 1.0000x reference)
//
#include <hip/hip_runtime.h>

#define TT 512
#define BB 1024
#define FF 32
#define HH 64
#define GG 256   // 4*H gates per direction

// Static device scratch (ws_size-independent). Fully overwritten every call.
__device__ float g_h1[(size_t)TT * BB * 2 * HH];   // [T][B][128] layer-1 input
__device__ float g_pre0[(size_t)2 * TT * BB * GG]; // [dir][T][B][256] layer-0 pre-gates
__device__ float g_pre1[(size_t)TT * BB * GG];     // [T][B][256] layer-1 fwd pre-gates
__device__ float g_hf[(size_t)BB * HH];            // [B][64] final fwd h of layer1

__device__ __forceinline__ float fsigm(float x) {
    float e = __builtin_amdgcn_exp2f(x * -1.44269504088896f);
    return __builtin_amdgcn_rcpf(1.0f + e);
}
__device__ __forceinline__ float ftanh(float x) {
    float e = __builtin_amdgcn_exp2f(x * -2.88539008177793f);
    return 2.0f * __builtin_amdgcn_rcpf(1.0f + e) - 1.0f;
}
// Wave-uniform broadcast via v_readlane (VALU, zero LDS-pipe cost).
__device__ __forceinline__ float rlane(float v, int l) {
    return __int_as_float(__builtin_amdgcn_readlane(__float_as_int(v), l));
}

// ---------------------------------------------------------------------------
// Layer-0 input pre-gates (unchanged).
// ---------------------------------------------------------------------------
__global__ __launch_bounds__(256, 4) void pre_gemm0(
    const float* __restrict__ x,      // [B][T][F]
    const float* __restrict__ w_ih,   // [2][G][F]
    const float* __restrict__ b_ih,
    const float* __restrict__ b_hh)
{
    const int tid = threadIdx.x;          // gate
    const int b   = blockIdx.x >> 1;
    const int dir = blockIdx.x & 1;

    __shared__ __align__(16) float4 w4[8 * 256];    // [kq][gate], 32 KB
    __shared__ __align__(16) float xbuf[2][256];    // 8 t-rows x 32 f, dbuf

    const float4* wsrc = (const float4*)(w_ih + ((size_t)dir * GG + tid) * FF);
#pragma unroll
    for (int kq = 0; kq < 8; ++kq) w4[kq * 256 + tid] = wsrc[kq];
    const float bias = b_ih[dir * GG + tid] + b_hh[dir * GG + tid];

    const float* xbase = x + (size_t)b * TT * FF;
    xbuf[0][tid] = xbase[tid];            // tile 0 (rows 0..7), coalesced
    const size_t OS = (size_t)BB * GG;

    for (int tc = 0; tc < 64; ++tc) {
        const int cur = tc & 1;
        __syncthreads();   // xbuf[cur] ready; prev reads of xbuf[1-cur] done

        float vnext = 0.f;
        if (tc + 1 < 64) vnext = xbase[(tc + 1) * 256 + tid];   // coalesced

        float a0 = bias, a1 = bias, a2 = bias, a3 = bias,
              a4 = bias, a5 = bias, a6 = bias, a7 = bias;
#pragma unroll
        for (int kq = 0; kq < 8; ++kq) {
            float4 wq = w4[kq * 256 + tid];
            const float4* xr = (const float4*)xbuf[cur];
            float4 q;
            q = xr[0 * 8 + kq]; a0 += q.x*wq.x + q.y*wq.y + q.z*wq.z + q.w*wq.w;
            q = xr[1 * 8 + kq]; a1 += q.x*wq.x + q.y*wq.y + q.z*wq.z + q.w*wq.w;
            q = xr[2 * 8 + kq]; a2 += q.x*wq.x + q.y*wq.y + q.z*wq.z + q.w*wq.w;
            q = xr[3 * 8 + kq]; a3 += q.x*wq.x + q.y*wq.y + q.z*wq.z + q.w*wq.w;
            q = xr[4 * 8 + kq]; a4 += q.x*wq.x + q.y*wq.y + q.z*wq.z + q.w*wq.w;
            q = xr[5 * 8 + kq]; a5 += q.x*wq.x + q.y*wq.y + q.z*wq.z + q.w*wq.w;
            q = xr[6 * 8 + kq]; a6 += q.x*wq.x + q.y*wq.y + q.z*wq.z + q.w*wq.w;
            q = xr[7 * 8 + kq]; a7 += q.x*wq.x + q.y*wq.y + q.z*wq.z + q.w*wq.w;
        }
        float* op = g_pre0 + (((size_t)dir * TT + tc * 8) * BB + b) * GG + tid;
        op[0] = a0; op[1 * OS] = a1; op[2 * OS] = a2; op[3 * OS] = a3;
        op[4 * OS] = a4; op[5 * OS] = a5; op[6 * OS] = a6; op[7 * OS] = a7;

        if (tc + 1 < 64) xbuf[1 - cur][tid] = vnext;
    }
}

// ---------------------------------------------------------------------------
// Wave-per-batch recurrent scan, v7: AGPR-resident weights.
// R1-R5 failed because the live set (256 weight regs + ~70 state) exceeds the
// 256 architectural-VGPR cap per wave -> allocator remats weight loads in-loop
// -> L2-BW-bound (~32 TB/s on weight re-reads). gfx950's 256 AGPRs are unused
// here: pin all 64 weight quads there via v_accvgpr_write/read inline asm
// ("a" constraint). VGPR live set drops to ~70 (feasible); in-loop cost is
// 256 accvgpr_read (1-cyc VALU) instead of L2 reloads + waits.
// L=0 processes TWO batches per wave (same weights, AGPR reads amortized):
// grid 1024 = dir x 512 batch-pairs. L=1: one batch, grid 1024.
// Lane l owns cell l and gates {l, 64+l, 128+l, 192+l}; h broadcast is one
// v_readlane feeding 4 (8 for B=2) FMAs; no LDS, no barriers in the T loop.
// ---------------------------------------------------------------------------
#define AQD(p) float p##_x, p##_y, p##_z, p##_w
#define AQW(p, src4) do { float4 q_ = (src4);                                  \
    asm volatile("v_accvgpr_write_b32 %0, %1" : "=a"(p##_x) : "v"(q_.x));      \
    asm volatile("v_accvgpr_write_b32 %0, %1" : "=a"(p##_y) : "v"(q_.y));      \
    asm volatile("v_accvgpr_write_b32 %0, %1" : "=a"(p##_z) : "v"(q_.z));      \
    asm volatile("v_accvgpr_write_b32 %0, %1" : "=a"(p##_w) : "v"(q_.w));      \
} while (0)
// volatile reads: prevents LICM from hoisting (re-creating 256 live VGPRs)
#define AQR(p) do {                                                            \
    asm volatile("v_accvgpr_read_b32 %0, %1" : "=v"(wx) : "a"(p##_x));         \
    asm volatile("v_accvgpr_read_b32 %0, %1" : "=v"(wy) : "a"(p##_y));         \
    asm volatile("v_accvgpr_read_b32 %0, %1" : "=v"(wz) : "a"(p##_z));         \
    asm volatile("v_accvgpr_read_b32 %0, %1" : "=v"(ww) : "a"(p##_w));         \
} while (0)

template <int L>
__global__ __attribute__((amdgpu_flat_work_group_size(64, 64),
                          amdgpu_waves_per_eu(1, 1)))
void lstm_scan(
    const float* __restrict__ w_hh)   // [2][G][64]
{
    constexpr bool B2 = (L == 0);
    const int l   = threadIdx.x;
    const int dir = (L == 0) ? (blockIdx.x & 1) : 0;
    const int b0  = (L == 0) ? (int)(blockIdx.x >> 1) * 2 : (int)blockIdx.x;
    const int b1  = b0 + 1;   // used only when B2

    const float* wbase = w_hh + (size_t)dir * GG * HH;

    // Weight rows for this lane's cell: i(l), f(64+l), g(128+l), o(192+l).
    const float4* pi_ = (const float4*)(wbase + (size_t)(0   + l) * HH);
    const float4* pf_ = (const float4*)(wbase + (size_t)(64  + l) * HH);
    const float4* pg_ = (const float4*)(wbase + (size_t)(128 + l) * HH);
    const float4* po_ = (const float4*)(wbase + (size_t)(192 + l) * HH);

    // 64 quads = 256 scalars -> 256 AGPRs (exactly the AGPR file).
    AQD(wi0);  AQD(wi1);  AQD(wi2);  AQD(wi3);
    AQD(wi4);  AQD(wi5);  AQD(wi6);  AQD(wi7);
    AQD(wi8);  AQD(wi9);  AQD(wi10); AQD(wi11);
    AQD(wi12); AQD(wi13); AQD(wi14); AQD(wi15);
    AQD(wf0);  AQD(wf1);  AQD(wf2);  AQD(wf3);
    AQD(wf4);  AQD(wf5);  AQD(wf6);  AQD(wf7);
    AQD(wf8);  AQD(wf9);  AQD(wf10); AQD(wf11);
    AQD(wf12); AQD(wf13); AQD(wf14); AQD(wf15);
    AQD(wg0);  AQD(wg1);  AQD(wg2);  AQD(wg3);
    AQD(wg4);  AQD(wg5);  AQD(wg6);  AQD(wg7);
    AQD(wg8);  AQD(wg9);  AQD(wg10); AQD(wg11);
    AQD(wg12); AQD(wg13); AQD(wg14); AQD(wg15);
    AQD(wo0);  AQD(wo1);  AQD(wo2);  AQD(wo3);
    AQD(wo4);  AQD(wo5);  AQD(wo6);  AQD(wo7);
    AQD(wo8);  AQD(wo9);  AQD(wo10); AQD(wo11);
    AQD(wo12); AQD(wo13); AQD(wo14); AQD(wo15);

    AQW(wi0,  pi_[0]);  AQW(wi1,  pi_[1]);  AQW(wi2,  pi_[2]);  AQW(wi3,  pi_[3]);
    AQW(wi4,  pi_[4]);  AQW(wi5,  pi_[5]);  AQW(wi6,  pi_[6]);  AQW(wi7,  pi_[7]);
    AQW(wi8,  pi_[8]);  AQW(wi9,  pi_[9]);  AQW(wi10, pi_[10]); AQW(wi11, pi_[11]);
    AQW(wi12, pi_[12]); AQW(wi13, pi_[13]); AQW(wi14, pi_[14]); AQW(wi15, pi_[15]);
    AQW(wf0,  pf_[0]);  AQW(wf1,  pf_[1]);  AQW(wf2,  pf_[2]);  AQW(wf3,  pf_[3]);
    AQW(wf4,  pf_[4]);  AQW(wf5,  pf_[5]);  AQW(wf6,  pf_[6]);  AQW(wf7,  pf_[7]);
    AQW(wf8,  pf_[8]);  AQW(wf9,  pf_[9]);  AQW(wf10, pf_[10]); AQW(wf11, pf_[11]);
    AQW(wf12, pf_[12]); AQW(wf13, pf_[13]); AQW(wf14, pf_[14]); AQW(wf15, pf_[15]);
    AQW(wg0,  pg_[0]);  AQW(wg1,  pg_[1]);  AQW(wg2,  pg_[2]);  AQW(wg3,  pg_[3]);
    AQW(wg4,  pg_[4]);  AQW(wg5,  pg_[5]);  AQW(wg6,  pg_[6]);  AQW(wg7,  pg_[7]);
    AQW(wg8,  pg_[8]);  AQW(wg9,  pg_[9]);  AQW(wg10, pg_[10]); AQW(wg11, pg_[11]);
    AQW(wg12, pg_[12]); AQW(wg13, pg_[13]); AQW(wg14, pg_[14]); AQW(wg15, pg_[15]);
    AQW(wo0,  po_[0]);  AQW(wo1,  po_[1]);  AQW(wo2,  po_[2]);  AQW(wo3,  po_[3]);
    AQW(wo4,  po_[4]);  AQW(wo5,  po_[5]);  AQW(wo6,  po_[6]);  AQW(wo7,  po_[7]);
    AQW(wo8,  po_[8]);  AQW(wo9,  po_[9]);  AQW(wo10, po_[10]); AQW(wo11, po_[11]);
    AQW(wo12, po_[12]); AQW(wo13, po_[13]); AQW(wo14, po_[14]); AQW(wo15, po_[15]);

    const float* pre = (L == 0) ? (g_pre0 + (size_t)dir * TT * BB * GG) : g_pre1;

    float c0 = 0.f, h0 = 0.f, c1 = 0.f, h1 = 0.f;

    // 2-deep pre-gate prefetch pipeline (explicit register rotation).
    const int t0 = dir ? (TT - 1) : 0;
    const int t1 = dir ? (TT - 2) : 1;
    const float* pp0a = pre + ((size_t)t0 * BB + b0) * GG;
    const float* pp1a = pre + ((size_t)t1 * BB + b0) * GG;
    float p_i0 = pp0a[l], p_f0 = pp0a[64 + l], p_g0 = pp0a[128 + l], p_o0 = pp0a[192 + l];
    float n_i0 = pp1a[l], n_f0 = pp1a[64 + l], n_g0 = pp1a[128 + l], n_o0 = pp1a[192 + l];
    float p_i1 = 0.f, p_f1 = 0.f, p_g1 = 0.f, p_o1 = 0.f;
    float n_i1 = 0.f, n_f1 = 0.f, n_g1 = 0.f, n_o1 = 0.f;
    if (B2) {
        const float* pp0b = pre + ((size_t)t0 * BB + b1) * GG;
        const float* pp1b = pre + ((size_t)t1 * BB + b1) * GG;
        p_i1 = pp0b[l]; p_f1 = pp0b[64 + l]; p_g1 = pp0b[128 + l]; p_o1 = pp0b[192 + l];
        n_i1 = pp1b[l]; n_f1 = pp1b[64 + l]; n_g1 = pp1b[128 + l]; n_o1 = pp1b[192 + l];
    }

#pragma unroll 1
    for (int s = 0; s < TT; ++s) {
        const int t = dir ? (TT - 1 - s) : s;

        // Issue prefetch for step s+2.
        float f_i0 = 0.f, f_f0 = 0.f, f_g0 = 0.f, f_o0 = 0.f;
        float f_i1 = 0.f, f_f1 = 0.f, f_g1 = 0.f, f_o1 = 0.f;
        if (s + 2 < TT) {
            const int tn = dir ? (TT - 3 - s) : (s + 2);
            const float* np0 = pre + ((size_t)tn * BB + b0) * GG;
            f_i0 = np0[l]; f_f0 = np0[64 + l]; f_g0 = np0[128 + l]; f_o0 = np0[192 + l];
            if (B2) {
                const float* np1 = pre + ((size_t)tn * BB + b1) * GG;
                f_i1 = np1[l]; f_f1 = np1[64 + l]; f_g1 = np1[128 + l]; f_o1 = np1[192 + l];
            }
        }

        float ai0 = p_i0, af0 = p_f0, ag0 = p_g0, ao0 = p_o0;
        float ai1 = p_i1, af1 = p_f1, ag1 = p_g1, ao1 = p_o1;

#define STEPQ(q) do {                                                          \
        float wx, wy, wz, ww;                                                  \
        const float s0 = rlane(h0, 4*q+0), s1 = rlane(h0, 4*q+1),              \
                    s2 = rlane(h0, 4*q+2), s3 = rlane(h0, 4*q+3);              \
        float u0 = 0.f, u1 = 0.f, u2 = 0.f, u3 = 0.f;                          \
        if (B2) { u0 = rlane(h1, 4*q+0); u1 = rlane(h1, 4*q+1);                \
                  u2 = rlane(h1, 4*q+2); u3 = rlane(h1, 4*q+3); }              \
        AQR(wi##q);                                                            \
        ai0 += s0*wx + s1*wy + s2*wz + s3*ww;                                  \
        if (B2) ai1 += u0*wx + u1*wy + u2*wz + u3*ww;                          \
        AQR(wf##q);                                                            \
        af0 += s0*wx + s1*wy + s2*wz + s3*ww;                                  \
        if (B2) af1 += u0*wx + u1*wy + u2*wz + u3*ww;                          \
        AQR(wg##q);                                                            \
        ag0 += s0*wx + s1*wy + s2*wz + s3*ww;                                  \
        if (B2) ag1 += u0*wx + u1*wy + u2*wz + u3*ww;                          \
        AQR(wo##q);                                                            \
        ao0 += s0*wx + s1*wy + s2*wz + s3*ww;                                  \
        if (B2) ao1 += u0*wx + u1*wy + u2*wz + u3*ww;                          \
    } while (0)

        STEPQ(0);  STEPQ(1);  STEPQ(2);  STEPQ(3);
        STEPQ(4);  STEPQ(5);  STEPQ(6);  STEPQ(7);
        STEPQ(8);  STEPQ(9);  STEPQ(10); STEPQ(11);
        STEPQ(12); STEPQ(13); STEPQ(14); STEPQ(15);
#undef STEPQ

        {
            const float ig = fsigm(ai0), fg = fsigm(af0),
                        gg = ftanh(ag0), og = fsigm(ao0);
            c0 = fg * c0 + ig * gg;
            h0 = og * ftanh(c0);
        }
        if (B2) {
            const float ig = fsigm(ai1), fg = fsigm(af1),
                        gg = ftanh(ag1), og = fsigm(ao1);
            c1 = fg * c1 + ig * gg;
            h1 = og * ftanh(c1);
        }

        if (L == 0) {
            g_h1[((size_t)t * BB + b0) * (2 * HH) + dir * HH + l] = h0;
            if (B2)
                g_h1[((size_t)t * BB + b1) * (2 * HH) + dir * HH + l] = h1;
        } else {
            if (s == TT - 1) g_hf[(size_t)b0 * HH + l] = h0;
        }

        // Rotate the prefetch pipeline.
        p_i0 = n_i0; p_f0 = n_f0; p_g0 = n_g0; p_o0 = n_o0;
        n_i0 = f_i0; n_f0 = f_f0; n_g0 = f_g0; n_o0 = f_o0;
        if (B2) {
            p_i1 = n_i1; p_f1 = n_f1; p_g1 = n_g1; p_o1 = n_o1;
            n_i1 = f_i1; n_f1 = f_f1; n_g1 = f_g1; n_o1 = f_o1;
        }
    }
}

// ---------------------------------------------------------------------------
// Layer-1 forward input pre-gates (unchanged).
// ---------------------------------------------------------------------------
__global__ __launch_bounds__(256, 2) void pre_gemm1(
    const float* __restrict__ w_ih,   // [2][G][128] (dir 0 used)
    const float* __restrict__ b_ih,
    const float* __restrict__ b_hh)
{
    const int tid  = threadIdx.x;
    const int gl   = tid & 127;
    const int rg   = tid >> 7;
    const int b    = blockIdx.x >> 1;
    const int gate = (blockIdx.x & 1) * 128 + gl;

    __shared__ __align__(16) float4 w4[28 * 128];       // quads 0..27, 56 KB
    __shared__ __align__(16) float4 hstg[2][8 * 32];    // 8 t-rows x 32 q, dbuf 8 KB

    const float4* wsrc = (const float4*)w_ih + (size_t)gate * 32;
#pragma unroll
    for (int i = 0; i < 14; ++i) {
        int kq = rg * 14 + i;
        w4[kq * 128 + gl] = wsrc[kq];
    }
    float4 wr0 = wsrc[28], wr1 = wsrc[29], wr2 = wsrc[30], wr3 = wsrc[31];
    const float bias = b_ih[gate] + b_hh[gate];

    const int srow = tid >> 5, sq = tid & 31;
    hstg[0][srow * 32 + sq] =
        *((const float4*)(g_h1 + ((size_t)srow * BB + b) * 128) + sq);

    const size_t RS = (size_t)BB * GG;    // pre1 t-stride (floats)

    for (int tc = 0; tc < 64; ++tc) {
        const int cur = tc & 1;
        __syncthreads();   // hstg[cur] + w4 ready

        float4 vnext = make_float4(0.f, 0.f, 0.f, 0.f);
        if (tc + 1 < 64)
            vnext = *((const float4*)(g_h1 +
                      ((size_t)((tc + 1) * 8 + srow) * BB + b) * 128) + sq);

        const float4* hr0 = &hstg[cur][(rg * 4 + 0) * 32];
        const float4* hr1 = &hstg[cur][(rg * 4 + 1) * 32];
        const float4* hr2 = &hstg[cur][(rg * 4 + 2) * 32];
        const float4* hr3 = &hstg[cur][(rg * 4 + 3) * 32];

        float a0 = bias, a1 = bias, a2 = bias, a3 = bias;
#pragma unroll
        for (int kq = 0; kq < 28; ++kq) {
            float4 wq = w4[kq * 128 + gl];
            float4 q;
            q = hr0[kq]; a0 += q.x*wq.x + q.y*wq.y + q.z*wq.z + q.w*wq.w;
            q = hr1[kq]; a1 += q.x*wq.x + q.y*wq.y + q.z*wq.z + q.w*wq.w;
            q = hr2[kq]; a2 += q.x*wq.x + q.y*wq.y + q.z*wq.z + q.w*wq.w;
            q = hr3[kq]; a3 += q.x*wq.x + q.y*wq.y + q.z*wq.z + q.w*wq.w;
        }
        {
            float4 q;
            q = hr0[28]; a0 += q.x*wr0.x + q.y*wr0.y + q.z*wr0.z + q.w*wr0.w;
            q = hr1[28]; a1 += q.x*wr0.x + q.y*wr0.y + q.z*wr0.z + q.w*wr0.w;
            q = hr2[28]; a2 += q.x*wr0.x + q.y*wr0.y + q.z*wr0.z + q.w*wr0.w;
            q = hr3[28]; a3 += q.x*wr0.x + q.y*wr0.y + q.z*wr0.z + q.w*wr0.w;
            q = hr0[29]; a0 += q.x*wr1.x + q.y*wr1.y + q.z*wr1.z + q.w*wr1.w;
            q = hr1[29]; a1 += q.x*wr1.x + q.y*wr1.y + q.z*wr1.z + q.w*wr1.w;
            q = hr2[29]; a2 += q.x*wr1.x + q.y*wr1.y + q.z*wr1.z + q.w*wr1.w;
            q = hr3[29]; a3 += q.x*wr1.x + q.y*wr1.y + q.z*wr1.z + q.w*wr1.w;
            q = hr0[30]; a0 += q.x*wr2.x + q.y*wr2.y + q.z*wr2.z + q.w*wr2.w;
            q = hr1[30]; a1 += q.x*wr2.x + q.y*wr2.y + q.z*wr2.z + q.w*wr2.w;
            q = hr2[30]; a2 += q.x*wr2.x + q.y*wr2.y + q.z*wr2.z + q.w*wr2.w;
            q = hr3[30]; a3 += q.x*wr2.x + q.y*wr2.y + q.z*wr2.z + q.w*wr2.w;
            q = hr0[31]; a0 += q.x*wr3.x + q.y*wr3.y + q.z*wr3.z + q.w*wr3.w;
            q = hr1[31]; a1 += q.x*wr3.x + q.y*wr3.y + q.z*wr3.z + q.w*wr3.w;
            q = hr2[31]; a2 += q.x*wr3.x + q.y*wr3.y + q.z*wr3.z + q.w*wr3.w;
            q = hr3[31]; a3 += q.x*wr3.x + q.y*wr3.y + q.z*wr3.z + q.w*wr3.w;
        }
        {
            const int tb = tc * 8 + rg * 4;
            float* op = g_pre1 + ((size_t)tb * BB + b) * GG + gate;
            op[0 * RS] = a0; op[1 * RS] = a1; op[2 * RS] = a2; op[3 * RS] = a3;
        }
        if (tc + 1 < 64) hstg[1 - cur][srow * 32 + sq] = vnext;
    }
}

// ---------------------------------------------------------------------------
// Layer 1 backward single step (zero state on h1[T-1]) + FC head (unchanged).
// ---------------------------------------------------------------------------
#define FMAC4(W, P0, P1, P2, P3, K) do{                                   \
    float4 v_;                                                           \
    v_ = (P0)[K]; acc0 += W.x*v_.x; acc0 += W.y*v_.y; acc0 += W.z*v_.z; acc0 += W.w*v_.w; \
    v_ = (P1)[K]; acc1 += W.x*v_.x; acc1 += W.y*v_.y; acc1 += W.z*v_.z; acc1 += W.w*v_.w; \
    v_ = (P2)[K]; acc2 += W.x*v_.x; acc2 += W.y*v_.y; acc2 += W.z*v_.z; acc2 += W.w*v_.w; \
    v_ = (P3)[K]; acc3 += W.x*v_.x; acc3 += W.y*v_.y; acc3 += W.z*v_.z; acc3 += W.w*v_.w; \
}while(0)

__global__ __launch_bounds__(256, 2) void lstm_final(
    const float* __restrict__ w_ih,   // [2][G][128] (dir 1)
    const float* __restrict__ b_ih,
    const float* __restrict__ b_hh,
    const float* __restrict__ fc_w,   // [2][128]
    const float* __restrict__ fc_b,   // [2]
    float* __restrict__ out)          // [B][2]
{
    const int tid = threadIdx.x;
    const int b0  = blockIdx.x * 4;

    __shared__ __align__(16) float x_lds[4][128];
    __shared__ __align__(16) float gact[4][GG];
    __shared__ __align__(16) float last[4][128];

#pragma unroll
    for (int r = 0; r < 2; ++r) {
        int idx = tid + r * 256;
        int b = idx >> 7, col = idx & 127;
        x_lds[b][col] = g_h1[((size_t)(TT - 1) * BB + (b0 + b)) * 128 + col];
    }

    const float4* p = (const float4*)(w_ih + ((size_t)GG + tid) * 128);
    float4 w0 = p[0],  w1 = p[1],  w2 = p[2],  w3 = p[3],  w4 = p[4],  w5 = p[5],
           w6 = p[6],  w7 = p[7],  w8 = p[8],  w9 = p[9],  w10 = p[10], w11 = p[11],
           w12 = p[12], w13 = p[13], w14 = p[14], w15 = p[15], w16 = p[16], w17 = p[17],
           w18 = p[18], w19 = p[19], w20 = p[20], w21 = p[21], w22 = p[22], w23 = p[23],
           w24 = p[24], w25 = p[25], w26 = p[26], w27 = p[27], w28 = p[28], w29 = p[29],
           w30 = p[30], w31 = p[31];
    const float bias = b_ih[GG + tid] + b_hh[GG + tid];
    __syncthreads();

    const float4* xb0 = (const float4*)x_lds[0];
    const float4* xb1 = (const float4*)x_lds[1];
    const float4* xb2 = (const float4*)x_lds[2];
    const float4* xb3 = (const float4*)x_lds[3];

    float acc0 = bias, acc1 = bias, acc2 = bias, acc3 = bias;
    FMAC4(w0, xb0, xb1, xb2, xb3, 0);   FMAC4(w1, xb0, xb1, xb2, xb3, 1);
    FMAC4(w2, xb0, xb1, xb2, xb3, 2);   FMAC4(w3, xb0, xb1, xb2, xb3, 3);
    FMAC4(w4, xb0, xb1, xb2, xb3, 4);   FMAC4(w5, xb0, xb1, xb2, xb3, 5);
    FMAC4(w6, xb0, xb1, xb2, xb3, 6);   FMAC4(w7, xb0, xb1, xb2, xb3, 7);
    FMAC4(w8, xb0, xb1, xb2, xb3, 8);   FMAC4(w9, xb0, xb1, xb2, xb3, 9);
    FMAC4(w10, xb0, xb1, xb2, xb3, 10); FMAC4(w11, xb0, xb1, xb2, xb3, 11);
    FMAC4(w12, xb0, xb1, xb2, xb3, 12); FMAC4(w13, xb0, xb1, xb2, xb3, 13);
    FMAC4(w14, xb0, xb1, xb2, xb3, 14); FMAC4(w15, xb0, xb1, xb2, xb3, 15);
    FMAC4(w16, xb0, xb1, xb2, xb3, 16); FMAC4(w17, xb0, xb1, xb2, xb3, 17);
    FMAC4(w18, xb0, xb1, xb2, xb3, 18); FMAC4(w19, xb0, xb1, xb2, xb3, 19);
    FMAC4(w20, xb0, xb1, xb2, xb3, 20); FMAC4(w21, xb0, xb1, xb2, xb3, 21);
    FMAC4(w22, xb0, xb1, xb2, xb3, 22); FMAC4(w23, xb0, xb1, xb2, xb3, 23);
    FMAC4(w24, xb0, xb1, xb2, xb3, 24); FMAC4(w25, xb0, xb1, xb2, xb3, 25);
    FMAC4(w26, xb0, xb1, xb2, xb3, 26); FMAC4(w27, xb0, xb1, xb2, xb3, 27);
    FMAC4(w28, xb0, xb1, xb2, xb3, 28); FMAC4(w29, xb0, xb1, xb2, xb3, 29);
    FMAC4(w30, xb0, xb1, xb2, xb3, 30); FMAC4(w31, xb0, xb1, xb2, xb3, 31);

    const bool is_g = ((tid >> 6) == 2);
    gact[0][tid] = is_g ? ftanh(acc0) : fsigm(acc0);
    gact[1][tid] = is_g ? ftanh(acc1) : fsigm(acc1);
    gact[2][tid] = is_g ? ftanh(acc2) : fsigm(acc2);
    gact[3][tid] = is_g ? ftanh(acc3) : fsigm(acc3);
    __syncthreads();

    {
        const int cb = tid >> 6, cj = tid & 63;
        float ig = gact[cb][cj];
        float gg = gact[cb][2 * HH + cj];
        float og = gact[cb][3 * HH + cj];
        float c = ig * gg;
        float h = og * ftanh(c);
        last[cb][HH + cj] = h;
        last[cb][cj] = g_hf[(size_t)(b0 + cb) * HH + cj];
    }
    __syncthreads();

    if (tid < 8) {
        int b = tid >> 1, o = tid & 1;
        float a = fc_b[o];
#pragma unroll
        for (int j = 0; j < 128; ++j) a += fc_w[o * 128 + j] * last[b][j];
        out[(size_t)(b0 + b) * 2 + o] = a;
    }
}

extern "C" void kernel_launch(void* const* d_in, const int* in_sizes, int n_in,
                              void* d_out, int out_size, void* d_ws, size_t ws_size,
                              hipStream_t stream) {
    const float* x     = (const float*)d_in[0];
    const float* w_ih0 = (const float*)d_in[1];
    const float* w_hh0 = (const float*)d_in[2];
    const float* b_ih0 = (const float*)d_in[3];
    const float* b_hh0 = (const float*)d_in[4];
    const float* w_ih1 = (const float*)d_in[5];
    const float* w_hh1 = (const float*)d_in[6];
    const float* b_ih1 = (const float*)d_in[7];
    const float* b_hh1 = (const float*)d_in[8];
    const float* fc_w  = (const float*)d_in[9];
    const float* fc_b  = (const float*)d_in[10];
    float* out = (float*)d_out;

    pre_gemm0<<<2048, 256, 0, stream>>>(x, w_ih0, b_ih0, b_hh0);
    lstm_scan<0><<<1024, 64, 0, stream>>>(w_hh0);
    pre_gemm1<<<2048, 256, 0, stream>>>(w_ih1, b_ih1, b_hh1);
    lstm_scan<1><<<1024, 64, 0, stream>>>(w_hh1);
    lstm_final<<<256, 256, 0, stream>>>(w_ih1, b_ih1, b_hh1, fc_w, fc_b, out);
}